// Round 5
// baseline (430.298 us; speedup 1.0000x reference)
//
#include <hip/hip_runtime.h>

// DIAGNOSTIC ROUND: R3 kernel (best so far: 2048 blocks x 4 rows, memcpy-order
// nontemporal W stream) with the W pass repeated K=4 times inside one dispatch
// so the matvec finally ranks in the rocprof top-5 and we read its counters
// directly (T_kernel = dispatch_dur/4, hbm_gbps, FETCH_SIZE -> L3 reuse?,
// VALUBusy, occupancy). Pass sums are averaged (x0.25); a data-dependent
// never-taken pointer bump stops the compiler CSE-ing identical loads across
// passes. Will be reverted to single-pass next round.

constexpr int IN_F  = 8192;
constexpr int OUT_F = 8192;
constexpr int ROWS_PER_BLOCK = 4;
constexpr int NT = 256;
constexpr int KPASS = 4;

typedef float v4f __attribute__((ext_vector_type(4)));

__global__ __launch_bounds__(NT) void matvec_f32_kernel(
    const float* __restrict__ x,
    const float* __restrict__ W,
    const float* __restrict__ bias,
    float* __restrict__ y) {

  const int t = threadIdx.x;
  const int blk = blockIdx.x;

  const v4f* __restrict__ xv = reinterpret_cast<const v4f*>(x);
  const v4f* __restrict__ Wc = reinterpret_cast<const v4f*>(
      W + (size_t)blk * ROWS_PER_BLOCK * IN_F);

  // Per-thread x fragment: 8 float4, register-resident, reused all passes.
  v4f xf[8];
#pragma unroll
  for (int j = 0; j < 8; ++j)
    xf[j] = xv[t + 256 * j];

  float rowtot[ROWS_PER_BLOCK] = {0.f, 0.f, 0.f, 0.f};
  size_t poff = 0;   // provably 0 at runtime, opaque to the compiler

  for (int p = 0; p < KPASS; ++p) {
    const v4f* Wp = Wc + poff;
#pragma unroll
    for (int r = 0; r < ROWS_PER_BLOCK; ++r) {
      v4f w[8];
#pragma unroll
      for (int j = 0; j < 8; ++j)
        w[j] = __builtin_nontemporal_load(&Wp[t + 256 * (8 * r + j)]);

      float p0 = 0.f, p1 = 0.f;
#pragma unroll
      for (int j = 0; j < 8; ++j) {
        p0 += w[j].x * xf[j].x + w[j].z * xf[j].z;
        p1 += w[j].y * xf[j].y + w[j].w * xf[j].w;
      }
      rowtot[r] += p0 + p1;
    }
    // Data-dependent, never-taken: defeats cross-pass load CSE.
    poff += (rowtot[0] > 1e30f) ? 1 : 0;
  }

  // Reduce each row across the wave, then across the 4 waves via LDS.
  __shared__ float red[4][ROWS_PER_BLOCK];
  const int lane = t & 63;
  const int wave = t >> 6;

#pragma unroll
  for (int r = 0; r < ROWS_PER_BLOCK; ++r) {
    float v = rowtot[r] * 0.25f;   // average the KPASS identical passes
#pragma unroll
    for (int off = 32; off > 0; off >>= 1)
      v += __shfl_down(v, off, 64);
    if (lane == 0) red[wave][r] = v;
  }
  __syncthreads();

  if (t < ROWS_PER_BLOCK) {
    float v = red[0][t] + red[1][t] + red[2][t] + red[3][t];
    y[blk * ROWS_PER_BLOCK + t] = v + bias[blk * ROWS_PER_BLOCK + t];
  }
}

extern "C" void kernel_launch(void* const* d_in, const int* in_sizes, int n_in,
                              void* d_out, int out_size, void* d_ws, size_t ws_size,
                              hipStream_t stream) {
  const float* x = (const float*)d_in[0];   // input  [8192]
  const float* W = (const float*)d_in[1];   // weight [8192*8192]
  const float* b = (const float*)d_in[2];   // bias   [8192]
  float* y = (float*)d_out;                 // output [8192] fp32

  dim3 grid(OUT_F / ROWS_PER_BLOCK);        // 2048 blocks
  dim3 block(NT);                           // 256 threads
  matvec_f32_kernel<<<grid, block, 0, stream>>>(x, W, b, y);
}

// Round 6
// 332.028 us; speedup vs baseline: 1.2960x; 1.2960x over previous
//
#include <hip/hip_runtime.h>

// y = W @ x + b ; W fp32 [8192,8192] (256 MiB) streamed once in memcpy order.
// FINAL (revert of R5 diagnostic to the best config, R3):
//   2048 blocks x 4 consecutive rows = 128 KB contiguous chunk per block,
//   read in pure sequential order (thread t, step s -> float4 t+256s): a 4-KB
//   sliding front per block. 8 blocks/CU -> 32 waves/CU (max occupancy).
//   col4 = (t+256s) mod 2048 = t + 256*(s mod 8): 8 x-float4s per thread stay
//   register-resident, reused for all 4 rows; x read once per block from L2.
//   W loads nontemporal (zero reuse within the pass). Wave shuffle-reduce per
//   row + 64-B LDS cross-wave reduction.
// Evidence (R5 diagnostic): marginal full-W pass = 32.2 us (8.3 TB/s, L3-warm
// aggregate ceiling); single-pass kernel <= ~65 us inside a ~334 us window
// dominated by fixed harness re-poison/restore traffic.

constexpr int IN_F  = 8192;
constexpr int OUT_F = 8192;
constexpr int ROWS_PER_BLOCK = 4;
constexpr int NT = 256;                 // threads per block (4 waves)

typedef float v4f __attribute__((ext_vector_type(4)));

__global__ __launch_bounds__(NT) void matvec_f32_kernel(
    const float* __restrict__ x,
    const float* __restrict__ W,
    const float* __restrict__ bias,
    float* __restrict__ y) {

  const int t = threadIdx.x;
  const int blk = blockIdx.x;

  const v4f* __restrict__ xv = reinterpret_cast<const v4f*>(x);
  const v4f* __restrict__ Wc = reinterpret_cast<const v4f*>(
      W + (size_t)blk * ROWS_PER_BLOCK * IN_F);

  // Per-thread x fragment: 8 float4 (coalesced, L2-resident), reused 4x.
  v4f xf[8];
#pragma unroll
  for (int j = 0; j < 8; ++j)
    xf[j] = xv[t + 256 * j];

  float acc[ROWS_PER_BLOCK];

#pragma unroll
  for (int r = 0; r < ROWS_PER_BLOCK; ++r) {
    // 8 nontemporal dwordx4 in flight (8 KB/wave), memcpy-ordered.
    v4f w[8];
#pragma unroll
    for (int j = 0; j < 8; ++j)
      w[j] = __builtin_nontemporal_load(&Wc[t + 256 * (8 * r + j)]);

    float p0 = 0.f, p1 = 0.f;
#pragma unroll
    for (int j = 0; j < 8; ++j) {
      p0 += w[j].x * xf[j].x + w[j].z * xf[j].z;
      p1 += w[j].y * xf[j].y + w[j].w * xf[j].w;
    }
    acc[r] = p0 + p1;
  }

  // Reduce each row across the wave, then across the 4 waves via LDS.
  __shared__ float red[4][ROWS_PER_BLOCK];
  const int lane = t & 63;
  const int wave = t >> 6;

#pragma unroll
  for (int r = 0; r < ROWS_PER_BLOCK; ++r) {
    float v = acc[r];
#pragma unroll
    for (int off = 32; off > 0; off >>= 1)
      v += __shfl_down(v, off, 64);
    if (lane == 0) red[wave][r] = v;
  }
  __syncthreads();

  if (t < ROWS_PER_BLOCK) {
    float v = red[0][t] + red[1][t] + red[2][t] + red[3][t];
    y[blk * ROWS_PER_BLOCK + t] = v + bias[blk * ROWS_PER_BLOCK + t];
  }
}

extern "C" void kernel_launch(void* const* d_in, const int* in_sizes, int n_in,
                              void* d_out, int out_size, void* d_ws, size_t ws_size,
                              hipStream_t stream) {
  const float* x = (const float*)d_in[0];   // input  [8192]
  const float* W = (const float*)d_in[1];   // weight [8192*8192]
  const float* b = (const float*)d_in[2];   // bias   [8192]
  float* y = (float*)d_out;                 // output [8192] fp32

  dim3 grid(OUT_F / ROWS_PER_BLOCK);        // 2048 blocks -> 8 blocks/CU
  dim3 block(NT);                           // 256 threads (4 waves)
  matvec_f32_kernel<<<grid, block, 0, stream>>>(x, W, b, y);
}